// Round 19
// baseline (116.261 us; speedup 1.0000x reference)
//
#include <hip/hip_runtime.h>
#include <hip/hip_bf16.h>
#include <math.h>

#define BATCH 4
#define SEQ 2049
#define WIN 64
#define M_ROWS 8196
#define M_PAD 8320

#define QT16 129
#define NKB 10
#define PSTR 168
#define CSTR 264
#define VGUARD 64
#define VW 2256
#define QKSTR 512
#define NSPLIT 33

typedef __attribute__((ext_vector_type(8))) short short8;
typedef __attribute__((ext_vector_type(4))) float f32x4;
typedef __hip_bfloat16 bf16;

__device__ __forceinline__ float b2f(short u) {
    union { unsigned int i; float f; } c;
    c.i = ((unsigned int)(unsigned short)u) << 16;
    return c.f;
}
__device__ __forceinline__ short f2b(float f) {
    bf16 h = __float2bfloat16(f);
    return *reinterpret_cast<short*>(&h);
}

// ---- prep: wq cvt (0..767) + RMSNorm1 (768..2816) + vT guard zero (2817..3328) ----
__global__ __launch_bounds__(256) void prep_kernel(
        const float* __restrict__ wq, bf16* __restrict__ oq,
        const float* __restrict__ x, const float* __restrict__ nw,
        bf16* __restrict__ h, short* __restrict__ vT) {
    const int bi = blockIdx.x, tid = threadIdx.x;
    if (bi < 768) {
        int i = bi * 256 + tid;
        oq[i] = __float2bfloat16(wq[i]);
        return;
    }
    if (bi >= 2817) {
        int rowid = (bi - 2817) * 2 + (tid >> 7);
        short* vr = vT + (size_t)rowid * VW;
        int t = tid & 127;
        if (t < 64) vr[t] = 0;
        else if (t - 64 < 143) vr[VGUARD + SEQ + (t - 64)] = 0;
        return;
    }
    int wid = tid >> 6, lane = tid & 63;
    int row = (bi - 768) * 4 + wid;
    if (row >= M_ROWS) return;
    const float4 v = reinterpret_cast<const float4*>(x + (size_t)row * 256)[lane];
    float ss = v.x * v.x + v.y * v.y + v.z * v.z + v.w * v.w;
    #pragma unroll
    for (int o = 1; o < 64; o <<= 1) ss += __shfl_xor(ss, o, 64);
    float r = rsqrtf(ss * (1.0f / 256.0f) + 1e-6f);
    const float4 wv = reinterpret_cast<const float4*>(nw)[lane];
    bf16* hp = h + (size_t)row * 256 + lane * 4;
    hp[0] = __float2bfloat16(v.x * r * wv.x);
    hp[1] = __float2bfloat16(v.y * r * wv.y);
    hp[2] = __float2bfloat16(v.z * r * wv.z);
    hp[3] = __float2bfloat16(v.w * r * wv.w);
}

// ---- QKV GEMM, BM=64, 2-phase double-buffered staging ----
__global__ __launch_bounds__(256) void gemm_qkv(
        const bf16* __restrict__ A, const bf16* __restrict__ B,
        const float* __restrict__ bias, bf16* __restrict__ qk, short* __restrict__ vT) {
    constexpr int ASZ = 8 * 64 * 8;     // shorts per A buffer
    constexpr int BSZ = 8 * 128 * 8;    // shorts per B buffer
    __shared__ __align__(16) short lA[2 * ASZ];   // 16 KB
    __shared__ __align__(16) short lB[2 * BSZ];   // 32 KB
    const int tid = threadIdx.x, lane = tid & 63, wid = tid >> 6;
    const int m0 = blockIdx.x * 64;
    const int n0 = blockIdx.y * 128;
    const int wr = wid >> 1, wc = wid & 1;
    const int r = lane & 15, g = lane >> 4;
    const int K = 256;

    auto stage = [&](int k0, int buf) {
        #pragma unroll
        for (int it = 0; it < 2; ++it) {
            int c = it * 256 + tid;
            int kc = c >> 6, row = c & 63;
            __builtin_amdgcn_global_load_lds(
                (const __attribute__((address_space(1))) void*)(A + (size_t)(m0 + row) * K + k0 + kc * 8),
                (__attribute__((address_space(3))) void*)&lA[buf * ASZ + c * 8], 16, 0, 0);
        }
        #pragma unroll
        for (int it = 0; it < 4; ++it) {
            int c = it * 256 + tid;
            int kc = c >> 7, row = c & 127;
            __builtin_amdgcn_global_load_lds(
                (const __attribute__((address_space(1))) void*)(B + (size_t)(n0 + row) * K + k0 + kc * 8),
                (__attribute__((address_space(3))) void*)&lB[buf * BSZ + c * 8], 16, 0, 0);
        }
    };

    f32x4 acc[2][4];
    #pragma unroll
    for (int i = 0; i < 2; i++)
        #pragma unroll
        for (int j = 0; j < 4; j++) acc[i][j] = (f32x4){0.f, 0.f, 0.f, 0.f};

    stage(0, 0);
    __syncthreads();
    int cur = 0;
    for (int k0 = 0; k0 < K; k0 += 64) {
        if (k0 + 64 < K) stage(k0 + 64, cur ^ 1);   // prefetch next tile (in flight during MFMA)
        #pragma unroll
        for (int kk = 0; kk < 2; kk++) {
            short8 a[2], b[4];
            #pragma unroll
            for (int mi = 0; mi < 2; mi++)
                a[mi] = *reinterpret_cast<const short8*>(&lA[cur * ASZ + ((kk * 4 + g) * 64 + wr * 32 + mi * 16 + r) * 8]);
            #pragma unroll
            for (int ni = 0; ni < 4; ni++)
                b[ni] = *reinterpret_cast<const short8*>(&lB[cur * BSZ + ((kk * 4 + g) * 128 + wc * 64 + ni * 16 + r) * 8]);
            #pragma unroll
            for (int mi = 0; mi < 2; mi++)
                #pragma unroll
                for (int ni = 0; ni < 4; ni++)
                    acc[mi][ni] = __builtin_amdgcn_mfma_f32_16x16x32_bf16(a[mi], b[ni], acc[mi][ni], 0, 0, 0);
        }
        __syncthreads();   // drains prefetch (vmcnt 0) + barrier: next buffer ready
        cur ^= 1;
    }

    const int c0 = lane & 15, r0 = (lane >> 4) * 4;
    const bool isV = (n0 >= 512);
    #pragma unroll
    for (int mi = 0; mi < 2; mi++) {
        #pragma unroll
        for (int ni = 0; ni < 4; ni++) {
            int col = n0 + wc * 64 + ni * 16 + c0;
            float bv = bias[col];
            #pragma unroll
            for (int j = 0; j < 4; j++) {
                int row = m0 + wr * 32 + mi * 16 + r0 + j;
                if (row < M_ROWS) {
                    float v = acc[mi][ni][j] + bv;
                    if (!isV) {
                        qk[(size_t)row * QKSTR + col] = __float2bfloat16(v);
                    } else {
                        int dcol = col - 512, hh = dcol >> 6, d = dcol & 63;
                        int bb = row >> 11;
                        int js = row - bb * SEQ;
                        if (js < 0) { bb--; js += SEQ; }
                        vT[((size_t)((bb * 4 + hh) * 64 + d)) * VW + VGUARD + js] = f2b(v);
                    }
                }
            }
        }
    }
}

// ---- generic LDS GEMM, 2-phase double-buffered (ffn1 <2,64,128>, ffn2 <1,64,64>) ----
template<int MODE, int BM, int BN>
__global__ __launch_bounds__(256) void gemm_lds_k(
        const bf16* __restrict__ A, const bf16* __restrict__ B,
        const float* __restrict__ bias, const float* __restrict__ resid,
        void* __restrict__ C, int M, int N, int K) {
    constexpr int FM = BM / 32, FN = BN / 32;
    constexpr int ASZ = 8 * BM * 8, BSZ = 8 * BN * 8;
    __shared__ __align__(16) short lA[2 * ASZ];
    __shared__ __align__(16) short lB[2 * BSZ];
    const int tid = threadIdx.x, lane = tid & 63, wid = tid >> 6;
    const int m0 = blockIdx.x * BM;
    const int n0 = blockIdx.y * BN;
    const int wr = wid >> 1, wc = wid & 1;
    const int r = lane & 15, g = lane >> 4;

    auto stage = [&](int k0, int buf) {
        #pragma unroll
        for (int it = 0; it < BM / 32; ++it) {
            int c = it * 256 + tid;
            int kc = c / BM, row = c % BM;
            __builtin_amdgcn_global_load_lds(
                (const __attribute__((address_space(1))) void*)(A + (size_t)(m0 + row) * K + k0 + kc * 8),
                (__attribute__((address_space(3))) void*)&lA[buf * ASZ + c * 8], 16, 0, 0);
        }
        #pragma unroll
        for (int it = 0; it < BN / 32; ++it) {
            int c = it * 256 + tid;
            int kc = c / BN, row = c % BN;
            __builtin_amdgcn_global_load_lds(
                (const __attribute__((address_space(1))) void*)(B + (size_t)(n0 + row) * K + k0 + kc * 8),
                (__attribute__((address_space(3))) void*)&lB[buf * BSZ + c * 8], 16, 0, 0);
        }
    };

    f32x4 acc[FM][FN];
    #pragma unroll
    for (int i = 0; i < FM; i++)
        #pragma unroll
        for (int j = 0; j < FN; j++) acc[i][j] = (f32x4){0.f, 0.f, 0.f, 0.f};

    stage(0, 0);
    __syncthreads();
    int cur = 0;
    for (int k0 = 0; k0 < K; k0 += 64) {
        if (k0 + 64 < K) stage(k0 + 64, cur ^ 1);
        #pragma unroll
        for (int kk = 0; kk < 2; kk++) {
            short8 a[FM], b[FN];
            #pragma unroll
            for (int mi = 0; mi < FM; mi++)
                a[mi] = *reinterpret_cast<const short8*>(&lA[cur * ASZ + ((kk * 4 + g) * BM + wr * (BM / 2) + mi * 16 + r) * 8]);
            #pragma unroll
            for (int ni = 0; ni < FN; ni++)
                b[ni] = *reinterpret_cast<const short8*>(&lB[cur * BSZ + ((kk * 4 + g) * BN + wc * (BN / 2) + ni * 16 + r) * 8]);
            #pragma unroll
            for (int mi = 0; mi < FM; mi++)
                #pragma unroll
                for (int ni = 0; ni < FN; ni++)
                    acc[mi][ni] = __builtin_amdgcn_mfma_f32_16x16x32_bf16(a[mi], b[ni], acc[mi][ni], 0, 0, 0);
        }
        __syncthreads();
        cur ^= 1;
    }

    const int c0 = lane & 15, r0 = (lane >> 4) * 4;
    #pragma unroll
    for (int mi = 0; mi < FM; mi++) {
        #pragma unroll
        for (int ni = 0; ni < FN; ni++) {
            int col = n0 + wc * (BN / 2) + ni * 16 + c0;
            float bv = bias[col];
            #pragma unroll
            for (int j = 0; j < 4; j++) {
                int row = m0 + wr * (BM / 2) + mi * 16 + r0 + j;
                if (row < M) {
                    float v = acc[mi][ni][j] + bv;
                    if (MODE == 2) v = 0.5f * v * (1.0f + erff(v * 0.70710678118654752f));
                    if (MODE == 1) {
                        v += resid[(size_t)row * N + col];
                        reinterpret_cast<float*>(C)[(size_t)row * N + col] = v;
                    } else {
                        reinterpret_cast<bf16*>(C)[(size_t)row * N + col] = __float2bfloat16(v);
                    }
                }
            }
        }
    }
}

// ---- q==0 split-K partials (0..527) + wo/w1/w2 cvt (528..1807) ----
__global__ __launch_bounds__(256) void attn_partial_k(const bf16* __restrict__ qkb,
        const short* __restrict__ vT, float* __restrict__ part,
        const float* __restrict__ wo_f, const float* __restrict__ w1_f,
        const float* __restrict__ w2_f, bf16* __restrict__ wob,
        bf16* __restrict__ w1b, bf16* __restrict__ w2b) {
    const int tid = threadIdx.x;
    if (blockIdx.x >= 528) {
        int i = (blockIdx.x - 528) * 256 + tid;
        if (i < 65536)       wob[i]          = __float2bfloat16(wo_f[i]);
        else if (i < 196608) w1b[i - 65536]  = __float2bfloat16(w1_f[i - 65536]);
        else                 w2b[i - 196608] = __float2bfloat16(w2_f[i - 196608]);
        return;
    }
    __shared__ float q_s[64];
    __shared__ float p_s[64];
    __shared__ float meta[2];
    __shared__ float osum[4][64];
    const short* qks = (const short*)qkb;
    const int lane = tid & 63, wid = tid >> 6;
    const int bh = blockIdx.x / NSPLIT, s = blockIdx.x % NSPLIT;
    const int b = bh >> 2, h = bh & 3;
    const size_t base = (size_t)b * SEQ;
    const int j0 = s * 64;
    if (tid < 64) q_s[tid] = b2f(qks[base * QKSTR + h * 64 + tid]);
    __syncthreads();
    if (wid == 0) {
        int j = j0 + lane;
        float sc = -1e30f;
        if (j < SEQ) {
            const short8* kp = reinterpret_cast<const short8*>(qks + (base + j) * QKSTR + 256 + h * 64);
            float acc = 0.f;
            #pragma unroll
            for (int d8 = 0; d8 < 8; ++d8) {
                short8 kv = kp[d8];
                #pragma unroll
                for (int e = 0; e < 8; ++e) acc += q_s[d8 * 8 + e] * b2f(kv[e]);
            }
            sc = acc * 0.125f;
        }
        float mx = sc;
        #pragma unroll
        for (int o = 1; o < 64; o <<= 1) mx = fmaxf(mx, __shfl_xor(mx, o, 64));
        float pv = (j < SEQ) ? expf(sc - mx) : 0.f;
        p_s[lane] = pv;
        float l = pv;
        #pragma unroll
        for (int o = 1; o < 64; o <<= 1) l += __shfl_xor(l, o, 64);
        if (lane == 0) { meta[0] = mx; meta[1] = l; }
    }
    __syncthreads();
    const short* vrow = vT + ((size_t)bh * 64 + lane) * VW + VGUARD + j0;
    float oa = 0.f;
    #pragma unroll
    for (int i0 = 0; i0 < 16; i0++) {
        int i = wid + i0 * 4;
        if (j0 + i < SEQ) oa += p_s[i] * b2f(vrow[i]);
    }
    osum[wid][lane] = oa;
    __syncthreads();
    if (wid == 0) {
        float o = osum[0][lane] + osum[1][lane] + osum[2][lane] + osum[3][lane];
        float* pp = part + (size_t)blockIdx.x * 66;
        pp[lane] = o;
        if (lane == 0) { pp[64] = meta[0]; pp[65] = meta[1]; }
    }
}

// ---- fused: banded attention + q0 combine + out-proj + resid + RMSNorm2 ----
__global__ __launch_bounds__(256) void attn_or_k(
        const bf16* __restrict__ qkb, const short* __restrict__ vT,
        const float* __restrict__ part, const bf16* __restrict__ wo,
        const float* __restrict__ ob, const float* __restrict__ x,
        const float* __restrict__ nw, float* __restrict__ x1, bf16* __restrict__ h2) {
    __shared__ short pl[4 * 16 * PSTR];
    __shared__ short cl[16 * CSTR];
    __shared__ float osq[4][16];
    const short* qks = (const short*)qkb;
    const int tid = threadIdx.x, lane = tid & 63, h = tid >> 6;
    const int qt = blockIdx.x % QT16;
    const int b = blockIdx.x / QT16;
    const int bh = b * 4 + h;
    const size_t rbase = (size_t)b * SEQ;
    const int q0 = qt * 16;
    const int jbase = q0 - 64;
    const int lrow = lane & 15;
    const int koff = (lane >> 4) * 8;
    const int c0 = lrow, r0 = (lane >> 4) * 4;

    int qrow = q0 + lrow; if (qrow > SEQ - 1) qrow = SEQ - 1;
    const short* qp = qks + (rbase + qrow) * QKSTR + h * 64;
    short8 aq0 = *reinterpret_cast<const short8*>(qp + koff);
    short8 aq1 = *reinterpret_cast<const short8*>(qp + 32 + koff);

    const short* k0p = qks + rbase * QKSTR + 256 + h * 64;
    short8 k0a = *reinterpret_cast<const short8*>(k0p + koff);
    short8 k0b = *reinterpret_cast<const short8*>(k0p + 32 + koff);
    float s0 = 0.f;
    #pragma unroll
    for (int e = 0; e < 8; e++)
        s0 += b2f(aq0[e]) * b2f(k0a[e]) + b2f(aq1[e]) * b2f(k0b[e]);
    s0 += __shfl_xor(s0, 16, 64);
    s0 += __shfl_xor(s0, 32, 64);

    f32x4 s[NKB];
    #pragma unroll
    for (int n = 0; n < NKB; n++) {
        int j = jbase + n * 16 + lrow;
        int jc = j < 0 ? 0 : (j > SEQ - 1 ? SEQ - 1 : j);
        const short* kp = qks + (rbase + jc) * QKSTR + 256 + h * 64;
        short8 bk0 = *reinterpret_cast<const short8*>(kp + koff);
        short8 bk1 = *reinterpret_cast<const short8*>(kp + 32 + koff);
        f32x4 acc = (f32x4){0.f, 0.f, 0.f, 0.f};
        acc = __builtin_amdgcn_mfma_f32_16x16x32_bf16(aq0, bk0, acc, 0, 0, 0);
        acc = __builtin_amdgcn_mfma_f32_16x16x32_bf16(aq1, bk1, acc, 0, 0, 0);
        s[n] = acc;
    }

    const float SC = 0.125f * 1.44269504088896340736f;
    const bool g1 = (jbase > 0);
    float s0q[4], m4[4];
    #pragma unroll
    for (int jj = 0; jj < 4; jj++) {
        s0q[jj] = __shfl(s0, r0 + jj, 64) * SC;
        m4[jj] = g1 ? s0q[jj] : -1e30f;
    }
    #pragma unroll
    for (int n = 0; n < NKB; n++) {
        int j = jbase + n * 16 + c0;
        bool jv = (j >= 0) && (j < SEQ);
        #pragma unroll
        for (int jj = 0; jj < 4; jj++) {
            int q = q0 + r0 + jj;
            int dd = q - j; if (dd < 0) dd = -dd;
            bool allowed = jv && (dd <= WIN || j == 0);
            float v = allowed ? s[n][jj] * SC : -1e30f;
            s[n][jj] = v;
            m4[jj] = fmaxf(m4[jj], v);
        }
    }
    #pragma unroll
    for (int o = 1; o < 16; o <<= 1) {
        #pragma unroll
        for (int jj = 0; jj < 4; jj++) m4[jj] = fmaxf(m4[jj], __shfl_xor(m4[jj], o, 64));
    }

    float p0[4], l4[4];
    #pragma unroll
    for (int jj = 0; jj < 4; jj++) {
        p0[jj] = g1 ? exp2f(s0q[jj] - m4[jj]) : 0.f;
        l4[jj] = p0[jj];
    }
    #pragma unroll
    for (int n = 0; n < NKB; n++) {
        #pragma unroll
        for (int jj = 0; jj < 4; jj++) {
            float pv = exp2f(s[n][jj] - m4[jj]);
            l4[jj] += pv;
            pl[(h * 16 + r0 + jj) * PSTR + n * 16 + c0] = f2b(pv);
        }
    }
    #pragma unroll
    for (int o = 1; o < 16; o <<= 1) {
        #pragma unroll
        for (int jj = 0; jj < 4; jj++) l4[jj] += __shfl_xor(l4[jj], o, 64);
    }

    f32x4 o4[4];
    #pragma unroll
    for (int dn = 0; dn < 4; dn++) o4[dn] = (f32x4){0.f, 0.f, 0.f, 0.f};
    #pragma unroll
    for (int ks = 0; ks < NKB / 2; ks++) {
        short8 ap = *reinterpret_cast<const short8*>(&pl[(h * 16 + lrow) * PSTR + ks * 32 + koff]);
        int cc = VGUARD + jbase + ks * 32 + koff;
        #pragma unroll
        for (int dn = 0; dn < 4; dn++) {
            short8 bv = *reinterpret_cast<const short8*>(
                vT + ((size_t)bh * 64 + dn * 16 + lrow) * VW + cc);
            o4[dn] = __builtin_amdgcn_mfma_f32_16x16x32_bf16(ap, bv, o4[dn], 0, 0, 0);
        }
    }

    #pragma unroll
    for (int jj = 0; jj < 4; jj++) {
        int q = q0 + r0 + jj;
        int ql = r0 + jj;
        float rl = 1.0f / l4[jj];
        #pragma unroll
        for (int dn = 0; dn < 4; dn++) {
            float v0 = b2f(vT[((size_t)bh * 64 + dn * 16 + c0) * VW + VGUARD]);
            float val = (o4[dn][jj] + p0[jj] * v0) * rl;
            if (q >= 1) cl[ql * CSTR + h * 64 + dn * 16 + c0] = f2b(val);
        }
    }

    if (qt == 0) {
        float m = (lane < NSPLIT) ? part[(size_t)(bh * NSPLIT + lane) * 66 + 64] : -1e30f;
        #pragma unroll
        for (int o2 = 1; o2 < 64; o2 <<= 1) m = fmaxf(m, __shfl_xor(m, o2, 64));
        float L = 0.f, ov = 0.f;
        for (int sp = 0; sp < NSPLIT; sp++) {
            const float* pp = part + (size_t)(bh * NSPLIT + sp) * 66;
            float w = expf(pp[64] - m);
            L += pp[65] * w;
            ov += pp[lane] * w;
        }
        cl[0 * CSTR + h * 64 + lane] = f2b(ov / L);
    }
    __syncthreads();

    f32x4 oacc[4];
    #pragma unroll
    for (int ni = 0; ni < 4; ni++) oacc[ni] = (f32x4){0.f, 0.f, 0.f, 0.f};
    #pragma unroll
    for (int ks = 0; ks < 8; ks++) {
        short8 a = *reinterpret_cast<const short8*>(&cl[lrow * CSTR + ks * 32 + koff]);
        #pragma unroll
        for (int ni = 0; ni < 4; ni++) {
            short8 bfrag = *reinterpret_cast<const short8*>(
                reinterpret_cast<const short*>(wo) + (size_t)(h * 64 + ni * 16 + lrow) * 256 + ks * 32 + koff);
            oacc[ni] = __builtin_amdgcn_mfma_f32_16x16x32_bf16(a, bfrag, oacc[ni], 0, 0, 0);
        }
    }

    float ssq[4];
    #pragma unroll
    for (int jj = 0; jj < 4; jj++) {
        int row = q0 + r0 + jj;
        float sq = 0.f;
        if (row < SEQ) {
            #pragma unroll
            for (int ni = 0; ni < 4; ni++) {
                int col = h * 64 + ni * 16 + c0;
                float v = oacc[ni][jj] + ob[col] + x[(rbase + row) * 256 + col];
                oacc[ni][jj] = v;
                x1[(rbase + row) * 256 + col] = v;
                sq += v * v;
            }
        }
        ssq[jj] = sq;
    }
    #pragma unroll
    for (int o2 = 1; o2 < 16; o2 <<= 1) {
        #pragma unroll
        for (int jj = 0; jj < 4; jj++) ssq[jj] += __shfl_xor(ssq[jj], o2, 64);
    }
    if (c0 == 0) {
        #pragma unroll
        for (int jj = 0; jj < 4; jj++) osq[h][r0 + jj] = ssq[jj];
    }
    __syncthreads();
    #pragma unroll
    for (int jj = 0; jj < 4; jj++) {
        int lr = r0 + jj;
        int row = q0 + lr;
        if (row < SEQ) {
            float tot = osq[0][lr] + osq[1][lr] + osq[2][lr] + osq[3][lr];
            float rs = rsqrtf(tot * (1.0f / 256.0f) + 1e-6f);
            #pragma unroll
            for (int ni = 0; ni < 4; ni++) {
                int col = h * 64 + ni * 16 + c0;
                h2[(rbase + row) * 256 + col] = __float2bfloat16(oacc[ni][jj] * rs * nw[col]);
            }
        }
    }
}

extern "C" void kernel_launch(void* const* d_in, const int* in_sizes, int n_in,
                              void* d_out, int out_size, void* d_ws, size_t ws_size,
                              hipStream_t stream) {
    const float* x         = (const float*)d_in[0];
    const float* norm1_w   = (const float*)d_in[1];
    const float* in_proj_w = (const float*)d_in[2];
    const float* in_proj_b = (const float*)d_in[3];
    const float* out_proj_w= (const float*)d_in[4];
    const float* out_proj_b= (const float*)d_in[5];
    const float* norm2_w   = (const float*)d_in[6];
    const float* w1        = (const float*)d_in[7];
    const float* b1        = (const float*)d_in[8];
    const float* w2        = (const float*)d_in[9];
    const float* b2        = (const float*)d_in[10];
    float* out = (float*)d_out;

    char* ws = (char*)d_ws;
    size_t off = 0;
    auto take = [&](size_t bytes) {
        char* q = ws + off;
        off = (off + bytes + 255) & ~(size_t)255;
        return q;
    };
    bf16* h_bf   = (bf16*)take((size_t)M_PAD * 256 * 2);
    bf16* qk_bf  = (bf16*)take((size_t)M_PAD * QKSTR * 2);
    float* x1    = (float*)take((size_t)M_PAD * 256 * 4);
    bf16* h2_bf  = (bf16*)take((size_t)M_PAD * 256 * 2);
    bf16* g_bf   = (bf16*)take((size_t)M_PAD * 512 * 2);
    bf16* wq_bf  = (bf16*)take(768 * 256 * 2);
    bf16* wo_bf  = (bf16*)take(256 * 256 * 2);
    bf16* w1_bf  = (bf16*)take(512 * 256 * 2);
    bf16* w2_bf  = (bf16*)take(256 * 512 * 2);
    float* part  = (float*)take((size_t)16 * NSPLIT * 66 * 4);
    short* vT    = (short*)take((size_t)16 * 64 * VW * 2);
    (void)ws_size; (void)in_sizes; (void)n_in; (void)out_size;

    prep_kernel<<<dim3(3329), dim3(256), 0, stream>>>(
        in_proj_w, wq_bf, x, norm1_w, h_bf, vT);
    gemm_qkv<<<dim3(130, 6), dim3(256), 0, stream>>>(h_bf, wq_bf, in_proj_b, qk_bf, vT);
    attn_partial_k<<<dim3(1808), dim3(256), 0, stream>>>(
        qk_bf, vT, part, out_proj_w, w1, w2, wo_bf, w1_bf, w2_bf);
    attn_or_k<<<dim3(4 * QT16), dim3(256), 0, stream>>>(
        qk_bf, vT, part, wo_bf, out_proj_b, x, norm2_w, x1, h2_bf);
    gemm_lds_k<2, 64, 128><<<dim3(130, 4), dim3(256), 0, stream>>>(
        h2_bf, w1_bf, b1, (const float*)nullptr, (void*)g_bf, M_ROWS, 512, 256);
    gemm_lds_k<1, 64, 64><<<dim3(130, 4), dim3(256), 0, stream>>>(
        g_bf, w2_bf, b2, x1, (void*)out, M_ROWS, 256, 512);
}

// Round 20
// 113.867 us; speedup vs baseline: 1.0210x; 1.0210x over previous
//
#include <hip/hip_runtime.h>
#include <hip/hip_bf16.h>
#include <math.h>

#define BATCH 4
#define SEQ 2049
#define WIN 64
#define M_ROWS 8196
#define M_PAD 8320

#define QT16 129
#define NKB 10
#define PSTR 168
#define CSTR 264
#define VGUARD 64
#define VW 2256
#define QKSTR 512
#define NSPLIT 33

typedef __attribute__((ext_vector_type(8))) short short8;
typedef __attribute__((ext_vector_type(4))) float f32x4;
typedef __hip_bfloat16 bf16;

__device__ __forceinline__ float b2f(short u) {
    union { unsigned int i; float f; } c;
    c.i = ((unsigned int)(unsigned short)u) << 16;
    return c.f;
}
__device__ __forceinline__ short f2b(float f) {
    bf16 h = __float2bfloat16(f);
    return *reinterpret_cast<short*>(&h);
}

// ---- prep: wq cvt (0..767) + RMSNorm1 (768..2816) + vT guard zero (2817..3328) ----
__global__ __launch_bounds__(256) void prep_kernel(
        const float* __restrict__ wq, bf16* __restrict__ oq,
        const float* __restrict__ x, const float* __restrict__ nw,
        bf16* __restrict__ h, short* __restrict__ vT) {
    const int bi = blockIdx.x, tid = threadIdx.x;
    if (bi < 768) {
        int i = bi * 256 + tid;
        oq[i] = __float2bfloat16(wq[i]);
        return;
    }
    if (bi >= 2817) {
        int rowid = (bi - 2817) * 2 + (tid >> 7);  // 1024 vT rows, 2 per block
        short* vr = vT + (size_t)rowid * VW;
        int t = tid & 127;
        if (t < 64) vr[t] = 0;                     // left guard
        else if (t - 64 < 143) vr[VGUARD + SEQ + (t - 64)] = 0;  // right guard
        return;
    }
    int wid = tid >> 6, lane = tid & 63;
    int row = (bi - 768) * 4 + wid;
    if (row >= M_ROWS) return;
    const float4 v = reinterpret_cast<const float4*>(x + (size_t)row * 256)[lane];
    float ss = v.x * v.x + v.y * v.y + v.z * v.z + v.w * v.w;
    #pragma unroll
    for (int o = 1; o < 64; o <<= 1) ss += __shfl_xor(ss, o, 64);
    float r = rsqrtf(ss * (1.0f / 256.0f) + 1e-6f);
    const float4 wv = reinterpret_cast<const float4*>(nw)[lane];
    bf16* hp = h + (size_t)row * 256 + lane * 4;
    hp[0] = __float2bfloat16(v.x * r * wv.x);
    hp[1] = __float2bfloat16(v.y * r * wv.y);
    hp[2] = __float2bfloat16(v.z * r * wv.z);
    hp[3] = __float2bfloat16(v.w * r * wv.w);
}

// ---- QKV GEMM, BM=64: cols<512 -> qk row-major; cols>=512 -> vT transposed ----
__global__ __launch_bounds__(256) void gemm_qkv(
        const bf16* __restrict__ A, const bf16* __restrict__ B,
        const float* __restrict__ bias, bf16* __restrict__ qk, short* __restrict__ vT) {
    __shared__ __align__(16) short lA[8 * 64 * 8];
    __shared__ __align__(16) short lB[8 * 128 * 8];
    const int tid = threadIdx.x, lane = tid & 63, wid = tid >> 6;
    const int m0 = blockIdx.x * 64;
    const int n0 = blockIdx.y * 128;
    const int wr = wid >> 1, wc = wid & 1;
    const int r = lane & 15, g = lane >> 4;
    const int K = 256;

    f32x4 acc[2][4];
    #pragma unroll
    for (int i = 0; i < 2; i++)
        #pragma unroll
        for (int j = 0; j < 4; j++) acc[i][j] = (f32x4){0.f, 0.f, 0.f, 0.f};

    for (int k0 = 0; k0 < K; k0 += 64) {
        #pragma unroll
        for (int it = 0; it < 2; ++it) {
            int c = it * 256 + tid;
            int kc = c >> 6, row = c & 63;
            __builtin_amdgcn_global_load_lds(
                (const __attribute__((address_space(1))) void*)(A + (size_t)(m0 + row) * K + k0 + kc * 8),
                (__attribute__((address_space(3))) void*)&lA[c * 8], 16, 0, 0);
        }
        #pragma unroll
        for (int it = 0; it < 4; ++it) {
            int c = it * 256 + tid;
            int kc = c >> 7, row = c & 127;
            __builtin_amdgcn_global_load_lds(
                (const __attribute__((address_space(1))) void*)(B + (size_t)(n0 + row) * K + k0 + kc * 8),
                (__attribute__((address_space(3))) void*)&lB[c * 8], 16, 0, 0);
        }
        __syncthreads();
        #pragma unroll
        for (int kk = 0; kk < 2; kk++) {
            short8 a[2], b[4];
            #pragma unroll
            for (int mi = 0; mi < 2; mi++)
                a[mi] = *reinterpret_cast<const short8*>(&lA[((kk * 4 + g) * 64 + wr * 32 + mi * 16 + r) * 8]);
            #pragma unroll
            for (int ni = 0; ni < 4; ni++)
                b[ni] = *reinterpret_cast<const short8*>(&lB[((kk * 4 + g) * 128 + wc * 64 + ni * 16 + r) * 8]);
            #pragma unroll
            for (int mi = 0; mi < 2; mi++)
                #pragma unroll
                for (int ni = 0; ni < 4; ni++)
                    acc[mi][ni] = __builtin_amdgcn_mfma_f32_16x16x32_bf16(a[mi], b[ni], acc[mi][ni], 0, 0, 0);
        }
        __syncthreads();
    }

    const int c0 = lane & 15, r0 = (lane >> 4) * 4;
    const bool isV = (n0 >= 512);
    #pragma unroll
    for (int mi = 0; mi < 2; mi++) {
        #pragma unroll
        for (int ni = 0; ni < 4; ni++) {
            int col = n0 + wc * 64 + ni * 16 + c0;
            float bv = bias[col];
            #pragma unroll
            for (int j = 0; j < 4; j++) {
                int row = m0 + wr * 32 + mi * 16 + r0 + j;
                if (row < M_ROWS) {
                    float v = acc[mi][ni][j] + bv;
                    if (!isV) {
                        qk[(size_t)row * QKSTR + col] = __float2bfloat16(v);
                    } else {
                        int dcol = col - 512, hh = dcol >> 6, d = dcol & 63;
                        int bb = row >> 11;
                        int js = row - bb * SEQ;
                        if (js < 0) { bb--; js += SEQ; }
                        vT[((size_t)((bb * 4 + hh) * 64 + d)) * VW + VGUARD + js] = f2b(v);
                    }
                }
            }
        }
    }
}

// ---- generic LDS GEMM (ffn1 <2,64,128>, ffn2 <1,64,64>) ----
template<int MODE, int BM, int BN>
__global__ __launch_bounds__(256) void gemm_lds_k(
        const bf16* __restrict__ A, const bf16* __restrict__ B,
        const float* __restrict__ bias, const float* __restrict__ resid,
        void* __restrict__ C, int M, int N, int K) {
    constexpr int FM = BM / 32, FN = BN / 32;
    __shared__ __align__(16) short lA[8 * BM * 8];
    __shared__ __align__(16) short lB[8 * BN * 8];
    const int tid = threadIdx.x, lane = tid & 63, wid = tid >> 6;
    const int m0 = blockIdx.x * BM;
    const int n0 = blockIdx.y * BN;
    const int wr = wid >> 1, wc = wid & 1;
    const int r = lane & 15, g = lane >> 4;

    f32x4 acc[FM][FN];
    #pragma unroll
    for (int i = 0; i < FM; i++)
        #pragma unroll
        for (int j = 0; j < FN; j++) acc[i][j] = (f32x4){0.f, 0.f, 0.f, 0.f};

    for (int k0 = 0; k0 < K; k0 += 64) {
        #pragma unroll
        for (int it = 0; it < BM / 32; ++it) {
            int c = it * 256 + tid;
            int kc = c / BM, row = c % BM;
            __builtin_amdgcn_global_load_lds(
                (const __attribute__((address_space(1))) void*)(A + (size_t)(m0 + row) * K + k0 + kc * 8),
                (__attribute__((address_space(3))) void*)&lA[c * 8], 16, 0, 0);
        }
        #pragma unroll
        for (int it = 0; it < BN / 32; ++it) {
            int c = it * 256 + tid;
            int kc = c / BN, row = c % BN;
            __builtin_amdgcn_global_load_lds(
                (const __attribute__((address_space(1))) void*)(B + (size_t)(n0 + row) * K + k0 + kc * 8),
                (__attribute__((address_space(3))) void*)&lB[c * 8], 16, 0, 0);
        }
        __syncthreads();
        #pragma unroll
        for (int kk = 0; kk < 2; kk++) {
            short8 a[FM], b[FN];
            #pragma unroll
            for (int mi = 0; mi < FM; mi++)
                a[mi] = *reinterpret_cast<const short8*>(&lA[((kk * 4 + g) * BM + wr * (BM / 2) + mi * 16 + r) * 8]);
            #pragma unroll
            for (int ni = 0; ni < FN; ni++)
                b[ni] = *reinterpret_cast<const short8*>(&lB[((kk * 4 + g) * BN + wc * (BN / 2) + ni * 16 + r) * 8]);
            #pragma unroll
            for (int mi = 0; mi < FM; mi++)
                #pragma unroll
                for (int ni = 0; ni < FN; ni++)
                    acc[mi][ni] = __builtin_amdgcn_mfma_f32_16x16x32_bf16(a[mi], b[ni], acc[mi][ni], 0, 0, 0);
        }
        __syncthreads();
    }

    const int c0 = lane & 15, r0 = (lane >> 4) * 4;
    #pragma unroll
    for (int mi = 0; mi < FM; mi++) {
        #pragma unroll
        for (int ni = 0; ni < FN; ni++) {
            int col = n0 + wc * (BN / 2) + ni * 16 + c0;
            float bv = bias[col];
            #pragma unroll
            for (int j = 0; j < 4; j++) {
                int row = m0 + wr * (BM / 2) + mi * 16 + r0 + j;
                if (row < M) {
                    float v = acc[mi][ni][j] + bv;
                    if (MODE == 2) v = 0.5f * v * (1.0f + erff(v * 0.70710678118654752f));
                    if (MODE == 1) {
                        v += resid[(size_t)row * N + col];
                        reinterpret_cast<float*>(C)[(size_t)row * N + col] = v;
                    } else {
                        reinterpret_cast<bf16*>(C)[(size_t)row * N + col] = __float2bfloat16(v);
                    }
                }
            }
        }
    }
}

// ---- q==0 split-K partials (0..527) + wo/w1/w2 cvt (528..1807) ----
__global__ __launch_bounds__(256) void attn_partial_k(const bf16* __restrict__ qkb,
        const short* __restrict__ vT, float* __restrict__ part,
        const float* __restrict__ wo_f, const float* __restrict__ w1_f,
        const float* __restrict__ w2_f, bf16* __restrict__ wob,
        bf16* __restrict__ w1b, bf16* __restrict__ w2b) {
    const int tid = threadIdx.x;
    if (blockIdx.x >= 528) {
        int i = (blockIdx.x - 528) * 256 + tid;       // 0..327679
        if (i < 65536)       wob[i]          = __float2bfloat16(wo_f[i]);
        else if (i < 196608) w1b[i - 65536]  = __float2bfloat16(w1_f[i - 65536]);
        else                 w2b[i - 196608] = __float2bfloat16(w2_f[i - 196608]);
        return;
    }
    __shared__ float q_s[64];
    __shared__ float p_s[64];
    __shared__ float meta[2];
    __shared__ float osum[4][64];
    const short* qks = (const short*)qkb;
    const int lane = tid & 63, wid = tid >> 6;
    const int bh = blockIdx.x / NSPLIT, s = blockIdx.x % NSPLIT;
    const int b = bh >> 2, h = bh & 3;
    const size_t base = (size_t)b * SEQ;
    const int j0 = s * 64;
    if (tid < 64) q_s[tid] = b2f(qks[base * QKSTR + h * 64 + tid]);
    __syncthreads();
    if (wid == 0) {
        int j = j0 + lane;
        float sc = -1e30f;
        if (j < SEQ) {
            const short8* kp = reinterpret_cast<const short8*>(qks + (base + j) * QKSTR + 256 + h * 64);
            float acc = 0.f;
            #pragma unroll
            for (int d8 = 0; d8 < 8; ++d8) {
                short8 kv = kp[d8];
                #pragma unroll
                for (int e = 0; e < 8; ++e) acc += q_s[d8 * 8 + e] * b2f(kv[e]);
            }
            sc = acc * 0.125f;
        }
        float mx = sc;
        #pragma unroll
        for (int o = 1; o < 64; o <<= 1) mx = fmaxf(mx, __shfl_xor(mx, o, 64));
        float pv = (j < SEQ) ? expf(sc - mx) : 0.f;
        p_s[lane] = pv;
        float l = pv;
        #pragma unroll
        for (int o = 1; o < 64; o <<= 1) l += __shfl_xor(l, o, 64);
        if (lane == 0) { meta[0] = mx; meta[1] = l; }
    }
    __syncthreads();
    const short* vrow = vT + ((size_t)bh * 64 + lane) * VW + VGUARD + j0;
    float oa = 0.f;
    #pragma unroll
    for (int i0 = 0; i0 < 16; i0++) {
        int i = wid + i0 * 4;
        if (j0 + i < SEQ) oa += p_s[i] * b2f(vrow[i]);
    }
    osum[wid][lane] = oa;
    __syncthreads();
    if (wid == 0) {
        float o = osum[0][lane] + osum[1][lane] + osum[2][lane] + osum[3][lane];
        float* pp = part + (size_t)blockIdx.x * 66;
        pp[lane] = o;
        if (lane == 0) { pp[64] = meta[0]; pp[65] = meta[1]; }
    }
}

// ---- fused: banded attention + q0 combine + out-proj + resid + RMSNorm2 ----
__global__ __launch_bounds__(256) void attn_or_k(
        const bf16* __restrict__ qkb, const short* __restrict__ vT,
        const float* __restrict__ part, const bf16* __restrict__ wo,
        const float* __restrict__ ob, const float* __restrict__ x,
        const float* __restrict__ nw, float* __restrict__ x1, bf16* __restrict__ h2) {
    __shared__ short pl[4 * 16 * PSTR];
    __shared__ short cl[16 * CSTR];
    __shared__ float osq[4][16];
    const short* qks = (const short*)qkb;
    const int tid = threadIdx.x, lane = tid & 63, h = tid >> 6;
    const int qt = blockIdx.x % QT16;
    const int b = blockIdx.x / QT16;
    const int bh = b * 4 + h;
    const size_t rbase = (size_t)b * SEQ;
    const int q0 = qt * 16;
    const int jbase = q0 - 64;
    const int lrow = lane & 15;
    const int koff = (lane >> 4) * 8;
    const int c0 = lrow, r0 = (lane >> 4) * 4;

    int qrow = q0 + lrow; if (qrow > SEQ - 1) qrow = SEQ - 1;
    const short* qp = qks + (rbase + qrow) * QKSTR + h * 64;
    short8 aq0 = *reinterpret_cast<const short8*>(qp + koff);
    short8 aq1 = *reinterpret_cast<const short8*>(qp + 32 + koff);

    const short* k0p = qks + rbase * QKSTR + 256 + h * 64;
    short8 k0a = *reinterpret_cast<const short8*>(k0p + koff);
    short8 k0b = *reinterpret_cast<const short8*>(k0p + 32 + koff);
    float s0 = 0.f;
    #pragma unroll
    for (int e = 0; e < 8; e++)
        s0 += b2f(aq0[e]) * b2f(k0a[e]) + b2f(aq1[e]) * b2f(k0b[e]);
    s0 += __shfl_xor(s0, 16, 64);
    s0 += __shfl_xor(s0, 32, 64);

    f32x4 s[NKB];
    #pragma unroll
    for (int n = 0; n < NKB; n++) {
        int j = jbase + n * 16 + lrow;
        int jc = j < 0 ? 0 : (j > SEQ - 1 ? SEQ - 1 : j);
        const short* kp = qks + (rbase + jc) * QKSTR + 256 + h * 64;
        short8 bk0 = *reinterpret_cast<const short8*>(kp + koff);
        short8 bk1 = *reinterpret_cast<const short8*>(kp + 32 + koff);
        f32x4 acc = (f32x4){0.f, 0.f, 0.f, 0.f};
        acc = __builtin_amdgcn_mfma_f32_16x16x32_bf16(aq0, bk0, acc, 0, 0, 0);
        acc = __builtin_amdgcn_mfma_f32_16x16x32_bf16(aq1, bk1, acc, 0, 0, 0);
        s[n] = acc;
    }

    const float SC = 0.125f * 1.44269504088896340736f;
    const bool g1 = (jbase > 0);
    float s0q[4], m4[4];
    #pragma unroll
    for (int jj = 0; jj < 4; jj++) {
        s0q[jj] = __shfl(s0, r0 + jj, 64) * SC;
        m4[jj] = g1 ? s0q[jj] : -1e30f;
    }
    #pragma unroll
    for (int n = 0; n < NKB; n++) {
        int j = jbase + n * 16 + c0;
        bool jv = (j >= 0) && (j < SEQ);
        #pragma unroll
        for (int jj = 0; jj < 4; jj++) {
            int q = q0 + r0 + jj;
            int dd = q - j; if (dd < 0) dd = -dd;
            bool allowed = jv && (dd <= WIN || j == 0);
            float v = allowed ? s[n][jj] * SC : -1e30f;
            s[n][jj] = v;
            m4[jj] = fmaxf(m4[jj], v);
        }
    }
    #pragma unroll
    for (int o = 1; o < 16; o <<= 1) {
        #pragma unroll
        for (int jj = 0; jj < 4; jj++) m4[jj] = fmaxf(m4[jj], __shfl_xor(m4[jj], o, 64));
    }

    float p0[4], l4[4];
    #pragma unroll
    for (int jj = 0; jj < 4; jj++) {
        p0[jj] = g1 ? exp2f(s0q[jj] - m4[jj]) : 0.f;
        l4[jj] = p0[jj];
    }
    #pragma unroll
    for (int n = 0; n < NKB; n++) {
        #pragma unroll
        for (int jj = 0; jj < 4; jj++) {
            float pv = exp2f(s[n][jj] - m4[jj]);
            l4[jj] += pv;
            pl[(h * 16 + r0 + jj) * PSTR + n * 16 + c0] = f2b(pv);
        }
    }
    #pragma unroll
    for (int o = 1; o < 16; o <<= 1) {
        #pragma unroll
        for (int jj = 0; jj < 4; jj++) l4[jj] += __shfl_xor(l4[jj], o, 64);
    }

    f32x4 o4[4];
    #pragma unroll
    for (int dn = 0; dn < 4; dn++) o4[dn] = (f32x4){0.f, 0.f, 0.f, 0.f};
    #pragma unroll
    for (int ks = 0; ks < NKB / 2; ks++) {
        short8 ap = *reinterpret_cast<const short8*>(&pl[(h * 16 + lrow) * PSTR + ks * 32 + koff]);
        int cc = VGUARD + jbase + ks * 32 + koff;
        #pragma unroll
        for (int dn = 0; dn < 4; dn++) {
            short8 bv = *reinterpret_cast<const short8*>(
                vT + ((size_t)bh * 64 + dn * 16 + lrow) * VW + cc);
            o4[dn] = __builtin_amdgcn_mfma_f32_16x16x32_bf16(ap, bv, o4[dn], 0, 0, 0);
        }
    }

    #pragma unroll
    for (int jj = 0; jj < 4; jj++) {
        int q = q0 + r0 + jj;
        int ql = r0 + jj;
        float rl = 1.0f / l4[jj];
        #pragma unroll
        for (int dn = 0; dn < 4; dn++) {
            float v0 = b2f(vT[((size_t)bh * 64 + dn * 16 + c0) * VW + VGUARD]);
            float val = (o4[dn][jj] + p0[jj] * v0) * rl;
            if (q >= 1) cl[ql * CSTR + h * 64 + dn * 16 + c0] = f2b(val);
        }
    }

    if (qt == 0) {
        float m = (lane < NSPLIT) ? part[(size_t)(bh * NSPLIT + lane) * 66 + 64] : -1e30f;
        #pragma unroll
        for (int o2 = 1; o2 < 64; o2 <<= 1) m = fmaxf(m, __shfl_xor(m, o2, 64));
        float L = 0.f, ov = 0.f;
        for (int sp = 0; sp < NSPLIT; sp++) {
            const float* pp = part + (size_t)(bh * NSPLIT + sp) * 66;
            float w = expf(pp[64] - m);
            L += pp[65] * w;
            ov += pp[lane] * w;
        }
        cl[0 * CSTR + h * 64 + lane] = f2b(ov / L);
    }
    __syncthreads();

    f32x4 oacc[4];
    #pragma unroll
    for (int ni = 0; ni < 4; ni++) oacc[ni] = (f32x4){0.f, 0.f, 0.f, 0.f};
    #pragma unroll
    for (int ks = 0; ks < 8; ks++) {
        short8 a = *reinterpret_cast<const short8*>(&cl[lrow * CSTR + ks * 32 + koff]);
        #pragma unroll
        for (int ni = 0; ni < 4; ni++) {
            short8 bfrag = *reinterpret_cast<const short8*>(
                reinterpret_cast<const short*>(wo) + (size_t)(h * 64 + ni * 16 + lrow) * 256 + ks * 32 + koff);
            oacc[ni] = __builtin_amdgcn_mfma_f32_16x16x32_bf16(a, bfrag, oacc[ni], 0, 0, 0);
        }
    }

    float ssq[4];
    #pragma unroll
    for (int jj = 0; jj < 4; jj++) {
        int row = q0 + r0 + jj;
        float sq = 0.f;
        if (row < SEQ) {
            #pragma unroll
            for (int ni = 0; ni < 4; ni++) {
                int col = h * 64 + ni * 16 + c0;
                float v = oacc[ni][jj] + ob[col] + x[(rbase + row) * 256 + col];
                oacc[ni][jj] = v;
                x1[(rbase + row) * 256 + col] = v;
                sq += v * v;
            }
        }
        ssq[jj] = sq;
    }
    #pragma unroll
    for (int o2 = 1; o2 < 16; o2 <<= 1) {
        #pragma unroll
        for (int jj = 0; jj < 4; jj++) ssq[jj] += __shfl_xor(ssq[jj], o2, 64);
    }
    if (c0 == 0) {
        #pragma unroll
        for (int jj = 0; jj < 4; jj++) osq[h][r0 + jj] = ssq[jj];
    }
    __syncthreads();
    #pragma unroll
    for (int jj = 0; jj < 4; jj++) {
        int lr = r0 + jj;
        int row = q0 + lr;
        if (row < SEQ) {
            float tot = osq[0][lr] + osq[1][lr] + osq[2][lr] + osq[3][lr];
            float rs = rsqrtf(tot * (1.0f / 256.0f) + 1e-6f);
            #pragma unroll
            for (int ni = 0; ni < 4; ni++) {
                int col = h * 64 + ni * 16 + c0;
                h2[(rbase + row) * 256 + col] = __float2bfloat16(oacc[ni][jj] * rs * nw[col]);
            }
        }
    }
}

extern "C" void kernel_launch(void* const* d_in, const int* in_sizes, int n_in,
                              void* d_out, int out_size, void* d_ws, size_t ws_size,
                              hipStream_t stream) {
    const float* x         = (const float*)d_in[0];
    const float* norm1_w   = (const float*)d_in[1];
    const float* in_proj_w = (const float*)d_in[2];
    const float* in_proj_b = (const float*)d_in[3];
    const float* out_proj_w= (const float*)d_in[4];
    const float* out_proj_b= (const float*)d_in[5];
    const float* norm2_w   = (const float*)d_in[6];
    const float* w1        = (const float*)d_in[7];
    const float* b1        = (const float*)d_in[8];
    const float* w2        = (const float*)d_in[9];
    const float* b2        = (const float*)d_in[10];
    float* out = (float*)d_out;

    char* ws = (char*)d_ws;
    size_t off = 0;
    auto take = [&](size_t bytes) {
        char* q = ws + off;
        off = (off + bytes + 255) & ~(size_t)255;
        return q;
    };
    bf16* h_bf   = (bf16*)take((size_t)M_PAD * 256 * 2);
    bf16* qk_bf  = (bf16*)take((size_t)M_PAD * QKSTR * 2);
    float* x1    = (float*)take((size_t)M_PAD * 256 * 4);
    bf16* h2_bf  = (bf16*)take((size_t)M_PAD * 256 * 2);
    bf16* g_bf   = (bf16*)take((size_t)M_PAD * 512 * 2);
    bf16* wq_bf  = (bf16*)take(768 * 256 * 2);
    bf16* wo_bf  = (bf16*)take(256 * 256 * 2);
    bf16* w1_bf  = (bf16*)take(512 * 256 * 2);
    bf16* w2_bf  = (bf16*)take(256 * 512 * 2);
    float* part  = (float*)take((size_t)16 * NSPLIT * 66 * 4);
    short* vT    = (short*)take((size_t)16 * 64 * VW * 2);
    (void)ws_size; (void)in_sizes; (void)n_in; (void)out_size;

    prep_kernel<<<dim3(3329), dim3(256), 0, stream>>>(
        in_proj_w, wq_bf, x, norm1_w, h_bf, vT);
    gemm_qkv<<<dim3(130, 6), dim3(256), 0, stream>>>(h_bf, wq_bf, in_proj_b, qk_bf, vT);
    attn_partial_k<<<dim3(1808), dim3(256), 0, stream>>>(
        qk_bf, vT, part, out_proj_w, w1, w2, wo_bf, w1_bf, w2_bf);
    attn_or_k<<<dim3(4 * QT16), dim3(256), 0, stream>>>(
        qk_bf, vT, part, wo_bf, out_proj_b, x, norm2_w, x1, h2_bf);
    gemm_lds_k<2, 64, 128><<<dim3(130, 4), dim3(256), 0, stream>>>(
        h2_bf, w1_bf, b1, (const float*)nullptr, (void*)g_bf, M_ROWS, 512, 256);
    gemm_lds_k<1, 64, 64><<<dim3(130, 4), dim3(256), 0, stream>>>(
        g_bf, w2_bf, b2, x1, (void*)out, M_ROWS, 256, 512);
}